// Round 7
// baseline (197.611 us; speedup 1.0000x reference)
//
#include <hip/hip_runtime.h>
#include <hip/hip_bf16.h>
#include <cmath>

#define D_MODEL 128
#define NUM_HEAD 4
#define HEAD_DIM 32
#define SEQ 4096
#define BATCH 2
#define RROWS 8     // token rows per out_proj block
#define QROWS 16    // token rows per qkv block

typedef __attribute__((ext_vector_type(8))) short short8;
typedef __attribute__((ext_vector_type(4))) float f32x4;

__device__ __forceinline__ float tof(float x) { return x; }
__device__ __forceinline__ float tof(__hip_bfloat16 x) { return __bfloat162float(x); }
__device__ __forceinline__ void storef(float* p, size_t i, float v) { p[i] = v; }
__device__ __forceinline__ void storef(__hip_bfloat16* p, size_t i, float v) { p[i] = __float2bfloat16(v); }

// manual RNE split: x = hi + lo in bf16, error ~2^-18 relative
__device__ __forceinline__ void split_bf16(float x, unsigned short& hi, unsigned short& lo)
{
    const unsigned u = __float_as_uint(x);
    const unsigned r = u + 0x7FFFu + ((u >> 16) & 1u);
    hi = (unsigned short)(r >> 16);
    const float hf = __uint_as_float((unsigned)hi << 16);
    const float lf = x - hf;
    const unsigned ul = __float_as_uint(lf);
    const unsigned rl = ul + 0x7FFFu + ((ul >> 16) & 1u);
    lo = (unsigned short)(rl >> 16);
}
// hi-only RNE round (for P, whose lo term is dropped in PV)
__device__ __forceinline__ unsigned short rne_bf16(float x)
{
    const unsigned u = __float_as_uint(x);
    return (unsigned short)((u + 0x7FFFu + ((u >> 16) & 1u)) >> 16);
}

// ---------------------------------------------------------------------------
// Kernel 0: fused prep (unchanged).
//   blocks 0..63    : inline dtype-detect + weight transpose to wt4[m][d>>2][e][4]
//   blocks 64..1087 : PE table pe[s][e] (same f64 pow/sin/cos numerics)
// ---------------------------------------------------------------------------
__global__ __launch_bounds__(256) void prep_kernel(
    const void* wq, const void* wk, const void* wv, const void* wo,
    float* __restrict__ wt4, float* __restrict__ pe, int* __restrict__ flagp)
{
    const int bx  = blockIdx.x;
    const int tid = threadIdx.x;
    __shared__ int sflag;

    if (bx < 64) {
        {
            int weird = 0;
            if (tid < 64) {
                const unsigned short* w16 = (const unsigned short*)wq;
#pragma unroll
                for (int j = 0; j < 4; ++j) {
                    const unsigned short v = w16[(tid * 4 + j) * 2 + 1];
                    const float x = __uint_as_float((unsigned)v << 16);
                    const float a = fabsf(x);
                    if (a > 1e20f || (a > 0.f && a < 1e-20f)) weird++;
                }
#pragma unroll
                for (int off = 32; off; off >>= 1) weird += __shfl_xor(weird, off);
                if (tid == 0) sflag = (weird < 32) ? 1 : 0;
            }
            __syncthreads();
        }
        const int flag = sflag;
        if (bx == 0 && tid == 0) *flagp = flag;

        const int m = bx >> 4;                        // matrix 0..3
        const void* w = (m == 0) ? wq : (m == 1) ? wk : (m == 2) ? wv : wo;
        const int item = (bx & 15) * 256 + tid;       // 0..4095 float4-items
        const int e  = item & 127;
        const int dq = item >> 7;                     // 0..31
        float4 v;
        if (flag) {
            v = *(const float4*)((const float*)w + (size_t)e * 128 + dq * 4);
        } else {
            const __hip_bfloat16* wb = (const __hip_bfloat16*)w + (size_t)e * 128 + dq * 4;
            v = make_float4(tof(wb[0]), tof(wb[1]), tof(wb[2]), tof(wb[3]));
        }
        *(float4*)&wt4[(((size_t)m * 32 + dq) * 128 + e) * 4] = v;   // coalesced
    } else {
        const int item = (bx - 64) * 256 + tid;       // 0..262143
        const int s = item >> 6;                      // 0..4095
        const int i = item & 63;                      // 0..63
        const double inv = 1.0 / pow(10000.0, (double)i / 64.0);
        const double a = (double)s * inv;
        float2 sc;
        sc.x = (float)sin(a);
        sc.y = (float)cos(a);
        *(float2*)&pe[(size_t)s * 128 + i * 2] = sc;  // coalesced 8B/lane
    }
}

// ---------------------------------------------------------------------------
// Kernel 1: x = embedding[seq] + PE(table);  Q/K/V = x @ W^T, SPLIT bf16.
// (unchanged)
// ---------------------------------------------------------------------------
template <typename T>
__device__ __forceinline__ void qkv_body(
    const int* __restrict__ seq, const T* __restrict__ emb,
    const float* __restrict__ wt4, const float* __restrict__ pe,
    unsigned short* __restrict__ Qhi, unsigned short* __restrict__ Qlo,
    unsigned short* __restrict__ Khi, unsigned short* __restrict__ Klo,
    unsigned short* __restrict__ Vthi, unsigned short* __restrict__ Vtlo)
{
    const int tid = threadIdx.x;
    const int e   = tid & 127;
    const int grp = tid >> 7;                 // 0..3 -> rows grp*4 .. grp*4+3
    const int r0  = blockIdx.x * QROWS;

    __shared__ __align__(16) float xs[QROWS][D_MODEL];
    __shared__ __align__(16) unsigned short vsh[2][QROWS][D_MODEL];

#pragma unroll
    for (int k = 0; k < 4; ++k) {
        const int idx = k * 512 + tid;        // 0..2047
        const int r  = idx >> 7;
        const int ee = idx & 127;
        const int srow = r0 + r;
        xs[r][ee] = tof(emb[(size_t)seq[srow] * D_MODEL + ee])
                  + pe[(size_t)(srow & (SEQ - 1)) * D_MODEL + ee];
    }
    __syncthreads();

    float aq[4], ak[4], av[4];
#pragma unroll
    for (int r = 0; r < 4; ++r) { aq[r] = 0.f; ak[r] = 0.f; av[r] = 0.f; }

    const int rbase = grp * 4;
    const float4* wq4 = (const float4*)wt4;          // matrix stride = 4096 float4
    const float4* wk4 = wq4 + 4096;
    const float4* wv4 = wq4 + 8192;

    for (int dq = 0; dq < 32; ++dq) {
        float4 xr[4];
#pragma unroll
        for (int r = 0; r < 4; ++r) xr[r] = *(const float4*)&xs[rbase + r][dq * 4];
        const float4 wq_ = wq4[dq * 128 + e];
        const float4 wk_ = wk4[dq * 128 + e];
        const float4 wv_ = wv4[dq * 128 + e];
#pragma unroll
        for (int r = 0; r < 4; ++r) {
            aq[r] += xr[r].x * wq_.x; aq[r] += xr[r].y * wq_.y;
            aq[r] += xr[r].z * wq_.z; aq[r] += xr[r].w * wq_.w;
            ak[r] += xr[r].x * wk_.x; ak[r] += xr[r].y * wk_.y;
            ak[r] += xr[r].z * wk_.z; ak[r] += xr[r].w * wk_.w;
            av[r] += xr[r].x * wv_.x; av[r] += xr[r].y * wv_.y;
            av[r] += xr[r].z * wv_.z; av[r] += xr[r].w * wv_.w;
        }
    }

    const float scale = 0.17677669529663687f;   // 1/sqrt(32) folded into Q
#pragma unroll
    for (int r = 0; r < 4; ++r) {
        const int row = rbase + r;
        const size_t o = (size_t)(r0 + row) * D_MODEL + e;
        unsigned short hi, lo;
        split_bf16(aq[r] * scale, hi, lo); Qhi[o] = hi; Qlo[o] = lo;
        split_bf16(ak[r], hi, lo);         Khi[o] = hi; Klo[o] = lo;
        split_bf16(av[r], hi, lo);         vsh[0][row][e] = hi; vsh[1][row][e] = lo;
    }
    __syncthreads();

    // coalesced V^T store
    {
        const int b  = r0 >> 12;
        const int s0 = r0 & (SEQ - 1);
        const int h  = s0 >> 10;
        const size_t vtb = (size_t)(b * 4 + h) * (32 * SEQ);
        const int hl = tid >> 8;             // 0..1 (hi/lo plane)
        const int d  = (tid >> 3) & 31;      // head-dim
        const int j  = tid & 7;              // k-octet within 64
        short8 tmp;
#pragma unroll
        for (int i = 0; i < 8; ++i) {
            const int kl = j * 8 + i;        // 0..63
            tmp[i] = (short)vsh[hl][kl >> 2][(kl & 3) * 32 + d];
        }
        unsigned short* dst = (hl ? Vtlo : Vthi) + vtb + (size_t)d * SEQ
                            + (size_t)(s0 & 1023) * 4 + j * 8;
        *(short8*)dst = tmp;
    }
}

__global__ __launch_bounds__(512, 4) void qkv_kernel(
    const int* __restrict__ seq, const void* emb,
    const float* __restrict__ wt4, const float* __restrict__ pe,
    unsigned short* Qhi, unsigned short* Qlo,
    unsigned short* Khi, unsigned short* Klo,
    unsigned short* Vthi, unsigned short* Vtlo,
    const int* __restrict__ flag)
{
    if (*flag)
        qkv_body<float>(seq, (const float*)emb, wt4, pe,
                        Qhi, Qlo, Khi, Klo, Vthi, Vtlo);
    else
        qkv_body<__hip_bfloat16>(seq, (const __hip_bfloat16*)emb, wt4, pe,
                                 Qhi, Qlo, Khi, Klo, Vthi, Vtlo);
}

// ---------------------------------------------------------------------------
// Kernel 2 (R24): MFMA flash attention, software-pipelined.
//   - fixed m=0 softmax (R23, exact by shift-invariance; scores bounded ~10)
//   - V loads for chunk c issued at TOP of body (~400cy before PV consumes)
//   - K loads for chunk c+1 issued inside body (QK never waits on memory)
//   - grid back to 256 blocks, ti-paired (65 units/block, perfectly balanced;
//     at ~100 VGPR only 1 block/CU fits anyway, so balance must be per-block)
// ---------------------------------------------------------------------------
__global__ __launch_bounds__(1024, 1) void attn_kernel(
    const unsigned short* __restrict__ Qhi, const unsigned short* __restrict__ Qlo,
    const unsigned short* __restrict__ Khi, const unsigned short* __restrict__ Klo,
    const unsigned short* __restrict__ Vthi, const unsigned short* __restrict__ Vtlo,
    float* __restrict__ A)
{
    const int bh   = blockIdx.x;
    const int pair = blockIdx.y;                  // 0..31
    const size_t baseQ  = (size_t)(bh >> 2) * SEQ * D_MODEL + (size_t)(bh & 3) * SEQ * HEAD_DIM;
    const size_t baseVt = (size_t)bh * (32 * SEQ);

    const int tid  = threadIdx.x;
    const int wid  = __builtin_amdgcn_readfirstlane(tid >> 6);
    const int lane = tid & 63;
    const int rt   = wid & 3;
    const int kh   = wid >> 2;
    const int quad = lane >> 4;
    const int col  = lane & 15;

    __shared__ float shbuf[16 * 560];
    float* pb = &shbuf[wid * 560];

#pragma unroll
    for (int ti = 0; ti < 2; ++ti) {
        const int qt = ti ? pair : (63 - pair);
        const int qrow0 = qt * 64 + rt * 16;

        short8 qhiF, qloF;
        {
            const size_t qo = baseQ + (size_t)(qrow0 + col) * HEAD_DIM + quad * 8;
            qhiF = *(const short8*)(Qhi + qo);
            qloF = *(const short8*)(Qlo + qo);
        }

        f32x4 O0 = {0.f, 0.f, 0.f, 0.f};
        f32x4 O1 = {0.f, 0.f, 0.f, 0.f};
        float l[4] = {0.f, 0.f, 0.f, 0.f};

        const int N   = 2 * (qt + 1);
        const int nb  = N >> 2, rem = N & 3;
        const int cnt  = nb + ((kh < rem) ? 1 : 0);
        const int cbeg = kh * nb + ((kh < rem) ? kh : rem);
        const int cend = cbeg + cnt;

        // preload K for first chunk (valid address even when cnt==0)
        short8 kc0h, kc0l, kc1h, kc1l;
        {
            const size_t k0o = baseQ + (size_t)(cbeg * 32 + col) * HEAD_DIM + quad * 8;
            const size_t k1o = k0o + (size_t)16 * HEAD_DIM;
            kc0h = *(const short8*)(Khi + k0o);
            kc0l = *(const short8*)(Klo + k0o);
            kc1h = *(const short8*)(Khi + k1o);
            kc1l = *(const short8*)(Klo + k1o);
        }

#pragma unroll 1
        for (int c = cbeg; c < cend; ++c) {
            const int kbase = c * 32;

            // V loads for THIS chunk -- issued first, consumed after softmax
            const size_t v0o = baseVt + (size_t)col * SEQ + kbase + quad * 8;
            const size_t v1o = v0o + (size_t)16 * SEQ;
            const short8 v0h = *(const short8*)(Vthi + v0o);
            const short8 v0l = *(const short8*)(Vtlo + v0o);
            const short8 v1h = *(const short8*)(Vthi + v1o);
            const short8 v1l = *(const short8*)(Vtlo + v1o);

            // K prefetch for NEXT chunk (clamped; covered by this chunk's work)
            const int cn = (c + 1 < cend) ? (c + 1) : c;
            const size_t kn0o = baseQ + (size_t)(cn * 32 + col) * HEAD_DIM + quad * 8;
            const size_t kn1o = kn0o + (size_t)16 * HEAD_DIM;
            const short8 kn0h = *(const short8*)(Khi + kn0o);
            const short8 kn0l = *(const short8*)(Klo + kn0o);
            const short8 kn1h = *(const short8*)(Khi + kn1o);
            const short8 kn1l = *(const short8*)(Klo + kn1o);

            f32x4 s0 = {0.f, 0.f, 0.f, 0.f};
            f32x4 s1 = {0.f, 0.f, 0.f, 0.f};
            s0 = __builtin_amdgcn_mfma_f32_16x16x32_bf16(qhiF, kc0h, s0, 0, 0, 0);
            s0 = __builtin_amdgcn_mfma_f32_16x16x32_bf16(qhiF, kc0l, s0, 0, 0, 0);
            s0 = __builtin_amdgcn_mfma_f32_16x16x32_bf16(qloF, kc0h, s0, 0, 0, 0);
            s1 = __builtin_amdgcn_mfma_f32_16x16x32_bf16(qhiF, kc1h, s1, 0, 0, 0);
            s1 = __builtin_amdgcn_mfma_f32_16x16x32_bf16(qhiF, kc1l, s1, 0, 0, 0);
            s1 = __builtin_amdgcn_mfma_f32_16x16x32_bf16(qloF, kc1h, s1, 0, 0, 0);

            // fixed m=0 softmax numerator: e = exp(|s|) where unmasked, else 0
#pragma unroll
            for (int r = 0; r < 4; ++r) {
                const int rowg = qrow0 + quad * 4 + r;
                const float e0 = (kbase + col      <= rowg) ? __expf(fabsf(s0[r])) : 0.f;
                const float e1 = (kbase + 16 + col <= rowg) ? __expf(fabsf(s1[r])) : 0.f;
                l[r] += e0 + e1;
                pb[(quad * 4 + r) * 34 + col]      = e0;
                pb[(quad * 4 + r) * 34 + 16 + col] = e1;
            }
            short8 ph;
            {
                const float* pr = &pb[col * 34 + quad * 8];
#pragma unroll
                for (int j = 0; j < 8; ++j) ph[j] = (short)rne_bf16(pr[j]);
            }

            O0 = __builtin_amdgcn_mfma_f32_16x16x32_bf16(ph, v0h, O0, 0, 0, 0);
            O0 = __builtin_amdgcn_mfma_f32_16x16x32_bf16(ph, v0l, O0, 0, 0, 0);
            O1 = __builtin_amdgcn_mfma_f32_16x16x32_bf16(ph, v1h, O1, 0, 0, 0);
            O1 = __builtin_amdgcn_mfma_f32_16x16x32_bf16(ph, v1l, O1, 0, 0, 0);

            kc0h = kn0h; kc0l = kn0l; kc1h = kn1h; kc1l = kn1l;
        }

#pragma unroll
        for (int off = 1; off < 16; off <<= 1) {
#pragma unroll
            for (int r = 0; r < 4; ++r) l[r] += __shfl_xor(l[r], off, 64);
        }

        __syncthreads();
        {
            float* cb = &shbuf[(rt * 4 + kh) * 560];
#pragma unroll
            for (int r = 0; r < 4; ++r) {
                const int row = quad * 4 + r;
                cb[row * 35 + col]      = O0[r];
                cb[row * 35 + 16 + col] = O1[r];
            }
            if (col == 0) {
#pragma unroll
                for (int r = 0; r < 4; ++r)
                    cb[(quad * 4 + r) * 35 + 32] = l[r];
            }
        }
        __syncthreads();
        if (kh == 0) {
            const int row = lane >> 2;
            const int d8  = (lane & 3) * 8;
            float L = 0.f;
#pragma unroll
            for (int q = 0; q < 4; ++q)
                L += shbuf[(rt * 4 + q) * 560 + row * 35 + 32];
            const float invL = 1.f / L;
            float* Ao = A + baseQ + (size_t)(qrow0 + row) * HEAD_DIM + d8;
#pragma unroll
            for (int d = 0; d < 8; ++d) {
                float o = 0.f;
#pragma unroll
                for (int q = 0; q < 4; ++q)
                    o += shbuf[(rt * 4 + q) * 560 + row * 35 + d8 + d];
                Ao[d] = o * invL;
            }
        }
        __syncthreads();
    }
}

// ---------------------------------------------------------------------------
// Kernel 3: out = att @ Wo^T (unchanged)
// ---------------------------------------------------------------------------
template <typename T>
__device__ __forceinline__ void out_proj_body(
    const float* __restrict__ att, const float* __restrict__ wo4t, T* __restrict__ out)
{
    const int tid = threadIdx.x;
    const int e   = tid & 127;
    const int grp = tid >> 7;                 // 0..1 -> rows grp*4 .. grp*4+3
    const int r0  = blockIdx.x * RROWS;

    __shared__ __align__(16) float xs[RROWS][D_MODEL];
#pragma unroll
    for (int k = 0; k < 4; ++k) {
        const int idx = k * 256 + tid;        // 0..1023
        xs[idx >> 7][idx & 127] = att[(size_t)(r0 + (idx >> 7)) * D_MODEL + (idx & 127)];
    }
    __syncthreads();

    float acc[4] = {0.f, 0.f, 0.f, 0.f};
    const int rbase = grp * 4;
    const float4* w4 = (const float4*)wo4t;

    for (int dq = 0; dq < 32; ++dq) {
        float4 xr[4];
#pragma unroll
        for (int r = 0; r < 4; ++r) xr[r] = *(const float4*)&xs[rbase + r][dq * 4];
        const float4 w_ = w4[dq * 128 + e];
#pragma unroll
        for (int r = 0; r < 4; ++r) {
            acc[r] += xr[r].x * w_.x; acc[r] += xr[r].y * w_.y;
            acc[r] += xr[r].z * w_.z; acc[r] += xr[r].w * w_.w;
        }
    }
#pragma unroll
    for (int r = 0; r < 4; ++r)
        storef(out, (size_t)(r0 + rbase + r) * D_MODEL + e, acc[r]);
}

__global__ __launch_bounds__(256, 4) void out_proj_kernel(
    const float* __restrict__ att, const float* __restrict__ wo4t, void* out,
    const int* __restrict__ flag)
{
    if (*flag)
        out_proj_body<float>(att, wo4t, (float*)out);
    else
        out_proj_body<__hip_bfloat16>(att, wo4t, (__hip_bfloat16*)out);
}

extern "C" void kernel_launch(void* const* d_in, const int* in_sizes, int n_in,
                              void* d_out, int out_size, void* d_ws, size_t ws_size,
                              hipStream_t stream) {
    const int* seq = (const int*)d_in[0];
    const void* emb = d_in[1];
    const void* wq  = d_in[2];
    const void* wk  = d_in[3];
    const void* wv  = d_in[4];
    const void* wo  = d_in[5];

    const size_t N = (size_t)BATCH * SEQ * D_MODEL;   // 1,048,576 elements
    int*            flag = (int*)d_ws;
    unsigned short* Qhi  = (unsigned short*)((char*)d_ws + 256);
    unsigned short* Qlo  = Qhi + N;
    unsigned short* Khi  = Qlo + N;
    unsigned short* Klo  = Khi + N;
    unsigned short* Vthi = Klo + N;
    unsigned short* Vtlo = Vthi + N;
    float*          A    = (float*)(Vtlo + N);        // fp32 attn output (4 MB)
    float*          wt4  = A + N;                     // 4 x 32 x 128 x 4 f32 (256 KB)
    float*          pe   = wt4 + 65536;               // 4096 x 128 f32 PE table (2 MB)

    prep_kernel<<<dim3(64 + 1024), dim3(256), 0, stream>>>(wq, wk, wv, wo, wt4, pe, flag);
    qkv_kernel<<<dim3(BATCH * SEQ / QROWS), dim3(512), 0, stream>>>(
        seq, emb, wt4, pe,
        Qhi, Qlo, Khi, Klo, Vthi, Vtlo, flag);
    attn_kernel<<<dim3(BATCH * NUM_HEAD, 32), dim3(1024), 0, stream>>>(
        Qhi, Qlo, Khi, Klo, Vthi, Vtlo, A);
    out_proj_kernel<<<dim3(BATCH * SEQ / RROWS), dim3(256), 0, stream>>>(
        A, wt4 + 49152, d_out, flag);
}

// Round 8
// 197.007 us; speedup vs baseline: 1.0031x; 1.0031x over previous
//
#include <hip/hip_runtime.h>
#include <hip/hip_bf16.h>
#include <cmath>

#define D_MODEL 128
#define NUM_HEAD 4
#define HEAD_DIM 32
#define SEQ 4096
#define BATCH 2
#define RROWS 8     // token rows per out_proj block
#define QROWS 16    // token rows per qkv block

typedef __attribute__((ext_vector_type(8))) short short8;
typedef __attribute__((ext_vector_type(4))) float f32x4;

__device__ __forceinline__ float tof(float x) { return x; }
__device__ __forceinline__ float tof(__hip_bfloat16 x) { return __bfloat162float(x); }
__device__ __forceinline__ void storef(float* p, size_t i, float v) { p[i] = v; }
__device__ __forceinline__ void storef(__hip_bfloat16* p, size_t i, float v) { p[i] = __float2bfloat16(v); }

// manual RNE split: x = hi + lo in bf16, error ~2^-18 relative
__device__ __forceinline__ void split_bf16(float x, unsigned short& hi, unsigned short& lo)
{
    const unsigned u = __float_as_uint(x);
    const unsigned r = u + 0x7FFFu + ((u >> 16) & 1u);
    hi = (unsigned short)(r >> 16);
    const float hf = __uint_as_float((unsigned)hi << 16);
    const float lf = x - hf;
    const unsigned ul = __float_as_uint(lf);
    const unsigned rl = ul + 0x7FFFu + ((ul >> 16) & 1u);
    lo = (unsigned short)(rl >> 16);
}
// hi-only RNE round (for P, whose lo term is dropped in PV)
__device__ __forceinline__ unsigned short rne_bf16(float x)
{
    const unsigned u = __float_as_uint(x);
    return (unsigned short)((u + 0x7FFFu + ((u >> 16) & 1u)) >> 16);
}

// ---------------------------------------------------------------------------
// Kernel 0: fused prep (unchanged).
// ---------------------------------------------------------------------------
__global__ __launch_bounds__(256) void prep_kernel(
    const void* wq, const void* wk, const void* wv, const void* wo,
    float* __restrict__ wt4, float* __restrict__ pe, int* __restrict__ flagp)
{
    const int bx  = blockIdx.x;
    const int tid = threadIdx.x;
    __shared__ int sflag;

    if (bx < 64) {
        {
            int weird = 0;
            if (tid < 64) {
                const unsigned short* w16 = (const unsigned short*)wq;
#pragma unroll
                for (int j = 0; j < 4; ++j) {
                    const unsigned short v = w16[(tid * 4 + j) * 2 + 1];
                    const float x = __uint_as_float((unsigned)v << 16);
                    const float a = fabsf(x);
                    if (a > 1e20f || (a > 0.f && a < 1e-20f)) weird++;
                }
#pragma unroll
                for (int off = 32; off; off >>= 1) weird += __shfl_xor(weird, off);
                if (tid == 0) sflag = (weird < 32) ? 1 : 0;
            }
            __syncthreads();
        }
        const int flag = sflag;
        if (bx == 0 && tid == 0) *flagp = flag;

        const int m = bx >> 4;                        // matrix 0..3
        const void* w = (m == 0) ? wq : (m == 1) ? wk : (m == 2) ? wv : wo;
        const int item = (bx & 15) * 256 + tid;       // 0..4095 float4-items
        const int e  = item & 127;
        const int dq = item >> 7;                     // 0..31
        float4 v;
        if (flag) {
            v = *(const float4*)((const float*)w + (size_t)e * 128 + dq * 4);
        } else {
            const __hip_bfloat16* wb = (const __hip_bfloat16*)w + (size_t)e * 128 + dq * 4;
            v = make_float4(tof(wb[0]), tof(wb[1]), tof(wb[2]), tof(wb[3]));
        }
        *(float4*)&wt4[(((size_t)m * 32 + dq) * 128 + e) * 4] = v;   // coalesced
    } else {
        const int item = (bx - 64) * 256 + tid;       // 0..262143
        const int s = item >> 6;                      // 0..4095
        const int i = item & 63;                      // 0..63
        const double inv = 1.0 / pow(10000.0, (double)i / 64.0);
        const double a = (double)s * inv;
        float2 sc;
        sc.x = (float)sin(a);
        sc.y = (float)cos(a);
        *(float2*)&pe[(size_t)s * 128 + i * 2] = sc;  // coalesced 8B/lane
    }
}

// ---------------------------------------------------------------------------
// Kernel 1: x = embedding[seq] + PE(table);  Q/K/V = x @ W^T, SPLIT bf16.
// (unchanged)
// ---------------------------------------------------------------------------
template <typename T>
__device__ __forceinline__ void qkv_body(
    const int* __restrict__ seq, const T* __restrict__ emb,
    const float* __restrict__ wt4, const float* __restrict__ pe,
    unsigned short* __restrict__ Qhi, unsigned short* __restrict__ Qlo,
    unsigned short* __restrict__ Khi, unsigned short* __restrict__ Klo,
    unsigned short* __restrict__ Vthi, unsigned short* __restrict__ Vtlo)
{
    const int tid = threadIdx.x;
    const int e   = tid & 127;
    const int grp = tid >> 7;                 // 0..3 -> rows grp*4 .. grp*4+3
    const int r0  = blockIdx.x * QROWS;

    __shared__ __align__(16) float xs[QROWS][D_MODEL];
    __shared__ __align__(16) unsigned short vsh[2][QROWS][D_MODEL];

#pragma unroll
    for (int k = 0; k < 4; ++k) {
        const int idx = k * 512 + tid;        // 0..2047
        const int r  = idx >> 7;
        const int ee = idx & 127;
        const int srow = r0 + r;
        xs[r][ee] = tof(emb[(size_t)seq[srow] * D_MODEL + ee])
                  + pe[(size_t)(srow & (SEQ - 1)) * D_MODEL + ee];
    }
    __syncthreads();

    float aq[4], ak[4], av[4];
#pragma unroll
    for (int r = 0; r < 4; ++r) { aq[r] = 0.f; ak[r] = 0.f; av[r] = 0.f; }

    const int rbase = grp * 4;
    const float4* wq4 = (const float4*)wt4;          // matrix stride = 4096 float4
    const float4* wk4 = wq4 + 4096;
    const float4* wv4 = wq4 + 8192;

    for (int dq = 0; dq < 32; ++dq) {
        float4 xr[4];
#pragma unroll
        for (int r = 0; r < 4; ++r) xr[r] = *(const float4*)&xs[rbase + r][dq * 4];
        const float4 wq_ = wq4[dq * 128 + e];
        const float4 wk_ = wk4[dq * 128 + e];
        const float4 wv_ = wv4[dq * 128 + e];
#pragma unroll
        for (int r = 0; r < 4; ++r) {
            aq[r] += xr[r].x * wq_.x; aq[r] += xr[r].y * wq_.y;
            aq[r] += xr[r].z * wq_.z; aq[r] += xr[r].w * wq_.w;
            ak[r] += xr[r].x * wk_.x; ak[r] += xr[r].y * wk_.y;
            ak[r] += xr[r].z * wk_.z; ak[r] += xr[r].w * wk_.w;
            av[r] += xr[r].x * wv_.x; av[r] += xr[r].y * wv_.y;
            av[r] += xr[r].z * wv_.z; av[r] += xr[r].w * wv_.w;
        }
    }

    const float scale = 0.17677669529663687f;   // 1/sqrt(32) folded into Q
#pragma unroll
    for (int r = 0; r < 4; ++r) {
        const int row = rbase + r;
        const size_t o = (size_t)(r0 + row) * D_MODEL + e;
        unsigned short hi, lo;
        split_bf16(aq[r] * scale, hi, lo); Qhi[o] = hi; Qlo[o] = lo;
        split_bf16(ak[r], hi, lo);         Khi[o] = hi; Klo[o] = lo;
        split_bf16(av[r], hi, lo);         vsh[0][row][e] = hi; vsh[1][row][e] = lo;
    }
    __syncthreads();

    // coalesced V^T store
    {
        const int b  = r0 >> 12;
        const int s0 = r0 & (SEQ - 1);
        const int h  = s0 >> 10;
        const size_t vtb = (size_t)(b * 4 + h) * (32 * SEQ);
        const int hl = tid >> 8;             // 0..1 (hi/lo plane)
        const int d  = (tid >> 3) & 31;      // head-dim
        const int j  = tid & 7;              // k-octet within 64
        short8 tmp;
#pragma unroll
        for (int i = 0; i < 8; ++i) {
            const int kl = j * 8 + i;        // 0..63
            tmp[i] = (short)vsh[hl][kl >> 2][(kl & 3) * 32 + d];
        }
        unsigned short* dst = (hl ? Vtlo : Vthi) + vtb + (size_t)d * SEQ
                            + (size_t)(s0 & 1023) * 4 + j * 8;
        *(short8*)dst = tmp;
    }
}

__global__ __launch_bounds__(512, 4) void qkv_kernel(
    const int* __restrict__ seq, const void* emb,
    const float* __restrict__ wt4, const float* __restrict__ pe,
    unsigned short* Qhi, unsigned short* Qlo,
    unsigned short* Khi, unsigned short* Klo,
    unsigned short* Vthi, unsigned short* Vtlo,
    const int* __restrict__ flag)
{
    if (*flag)
        qkv_body<float>(seq, (const float*)emb, wt4, pe,
                        Qhi, Qlo, Khi, Klo, Vthi, Vtlo);
    else
        qkv_body<__hip_bfloat16>(seq, (const __hip_bfloat16*)emb, wt4, pe,
                                 Qhi, Qlo, Khi, Klo, Vthi, Vtlo);
}

// ---------------------------------------------------------------------------
// Kernel 2 (R25): MFMA flash attention, TLP-maximized partial-sum form.
//   m=0 fixed softmax (verified exact) makes the kh combine a PLAIN SUM, so
//   each kh quarter becomes an independent 256-thread block writing partial
//   (O,l) to its own global plane; out_proj folds the 4-way sum + 1/L.
//   Grid 8x64x4 = 2048 blocks, 4 waves each, no barriers, launch_bounds(256,8)
//   -> 8 blocks/CU = 8 independent waves/SIMD hiding the ~1.3k-cy chunk chain
//   (the compiler-proof alternative to the R24 register prefetch it undid).
//   qt = by<32 ? by : 95-by keeps per-CU chunk totals exactly equal (130).
// ---------------------------------------------------------------------------
__global__ __launch_bounds__(256, 8) void attn_kernel(
    const unsigned short* __restrict__ Qhi, const unsigned short* __restrict__ Qlo,
    const unsigned short* __restrict__ Khi, const unsigned short* __restrict__ Klo,
    const unsigned short* __restrict__ Vthi, const unsigned short* __restrict__ Vtlo,
    float* __restrict__ Apart, float* __restrict__ lbuf)
{
    const int bh   = blockIdx.x;
    const int by   = blockIdx.y;                  // 0..63
    const int kh   = blockIdx.z;                  // 0..3
    const int qt   = (by < 32) ? by : 95 - by;    // complementary pairing per CU
    const size_t baseQ  = (size_t)(bh >> 2) * SEQ * D_MODEL + (size_t)(bh & 3) * SEQ * HEAD_DIM;
    const size_t baseVt = (size_t)bh * (32 * SEQ);

    const int tid  = threadIdx.x;
    const int wid  = __builtin_amdgcn_readfirstlane(tid >> 6);
    const int lane = tid & 63;
    const int rt   = wid;                         // 0..3
    const int quad = lane >> 4;
    const int col  = lane & 15;

    __shared__ float shbuf[4 * 544];
    float* pb = &shbuf[wid * 544];

    const int qrow0 = qt * 64 + rt * 16;

    short8 qhiF, qloF;
    {
        const size_t qo = baseQ + (size_t)(qrow0 + col) * HEAD_DIM + quad * 8;
        qhiF = *(const short8*)(Qhi + qo);
        qloF = *(const short8*)(Qlo + qo);
    }

    f32x4 O0 = {0.f, 0.f, 0.f, 0.f};
    f32x4 O1 = {0.f, 0.f, 0.f, 0.f};
    float l[4] = {0.f, 0.f, 0.f, 0.f};

    const int N   = 2 * (qt + 1);
    const int nb  = N >> 2, rem = N & 3;
    const int cnt  = nb + ((kh < rem) ? 1 : 0);
    const int cbeg = kh * nb + ((kh < rem) ? kh : rem);

    for (int c = cbeg; c < cbeg + cnt; ++c) {
        const int kbase = c * 32;
        const size_t k0o = baseQ + (size_t)(kbase + col) * HEAD_DIM + quad * 8;
        const size_t k1o = k0o + (size_t)16 * HEAD_DIM;
        const short8 k0h = *(const short8*)(Khi + k0o);
        const short8 k0l = *(const short8*)(Klo + k0o);
        const short8 k1h = *(const short8*)(Khi + k1o);
        const short8 k1l = *(const short8*)(Klo + k1o);

        f32x4 s0 = {0.f, 0.f, 0.f, 0.f};
        f32x4 s1 = {0.f, 0.f, 0.f, 0.f};
        s0 = __builtin_amdgcn_mfma_f32_16x16x32_bf16(qhiF, k0h, s0, 0, 0, 0);
        s0 = __builtin_amdgcn_mfma_f32_16x16x32_bf16(qhiF, k0l, s0, 0, 0, 0);
        s0 = __builtin_amdgcn_mfma_f32_16x16x32_bf16(qloF, k0h, s0, 0, 0, 0);
        s1 = __builtin_amdgcn_mfma_f32_16x16x32_bf16(qhiF, k1h, s1, 0, 0, 0);
        s1 = __builtin_amdgcn_mfma_f32_16x16x32_bf16(qhiF, k1l, s1, 0, 0, 0);
        s1 = __builtin_amdgcn_mfma_f32_16x16x32_bf16(qloF, k1h, s1, 0, 0, 0);

        // fixed m=0 softmax numerator: e = exp(|s|) where unmasked, else 0
#pragma unroll
        for (int r = 0; r < 4; ++r) {
            const int rowg = qrow0 + quad * 4 + r;
            const float e0 = (kbase + col      <= rowg) ? __expf(fabsf(s0[r])) : 0.f;
            const float e1 = (kbase + 16 + col <= rowg) ? __expf(fabsf(s1[r])) : 0.f;
            l[r] += e0 + e1;
            pb[(quad * 4 + r) * 34 + col]      = e0;
            pb[(quad * 4 + r) * 34 + 16 + col] = e1;
        }
        short8 ph;
        {
            const float* pr = &pb[col * 34 + quad * 8];
#pragma unroll
            for (int j = 0; j < 8; ++j) ph[j] = (short)rne_bf16(pr[j]);
        }
        const size_t v0o = baseVt + (size_t)col * SEQ + kbase + quad * 8;
        const size_t v1o = v0o + (size_t)16 * SEQ;
        const short8 v0h = *(const short8*)(Vthi + v0o);
        const short8 v0l = *(const short8*)(Vtlo + v0o);
        const short8 v1h = *(const short8*)(Vthi + v1o);
        const short8 v1l = *(const short8*)(Vtlo + v1o);

        O0 = __builtin_amdgcn_mfma_f32_16x16x32_bf16(ph, v0h, O0, 0, 0, 0);
        O0 = __builtin_amdgcn_mfma_f32_16x16x32_bf16(ph, v0l, O0, 0, 0, 0);
        O1 = __builtin_amdgcn_mfma_f32_16x16x32_bf16(ph, v1h, O1, 0, 0, 0);
        O1 = __builtin_amdgcn_mfma_f32_16x16x32_bf16(ph, v1l, O1, 0, 0, 0);
    }

    // row-sum of l across the 16 cols (4 xor steps within 16-lane groups)
#pragma unroll
    for (int off = 1; off < 16; off <<= 1) {
#pragma unroll
        for (int r = 0; r < 4; ++r) l[r] += __shfl_xor(l[r], off, 64);
    }

    // direct partial writes -- no cross-wave combine, no barriers
    float* Ap = Apart + (size_t)kh * (BATCH * SEQ * D_MODEL) + baseQ;
#pragma unroll
    for (int r = 0; r < 4; ++r) {
        const int row = qrow0 + quad * 4 + r;
        Ap[(size_t)row * HEAD_DIM + col]      = O0[r];
        Ap[(size_t)row * HEAD_DIM + 16 + col] = O1[r];
    }
    if (col == 0) {
        float* lp = lbuf + ((size_t)kh * (BATCH * NUM_HEAD) + bh) * SEQ;
#pragma unroll
        for (int r = 0; r < 4; ++r)
            lp[qrow0 + quad * 4 + r] = l[r];
    }
}

// ---------------------------------------------------------------------------
// Kernel 3 (R25): out = att @ Wo^T, with the 4-way kh partial sum + 1/L
// normalization folded into the staging loop.
// ---------------------------------------------------------------------------
template <typename T>
__device__ __forceinline__ void out_proj_body(
    const float* __restrict__ Apart, const float* __restrict__ lbuf,
    const float* __restrict__ wo4t, T* __restrict__ out)
{
    const int tid = threadIdx.x;
    const int e   = tid & 127;
    const int grp = tid >> 7;                 // 0..1 -> rows grp*4 .. grp*4+3
    const int r0  = blockIdx.x * RROWS;

    __shared__ __align__(16) float xs[RROWS][D_MODEL];
#pragma unroll
    for (int k = 0; k < 4; ++k) {
        const int idx = k * 256 + tid;        // 0..1023
        const int rr = idx >> 7;
        const int ee = idx & 127;
        const int gr = r0 + rr;               // global token row
        const int b  = gr >> 12;
        const int s  = gr & (SEQ - 1);
        const int bh = b * 4 + (s >> 10);
        const int hr = ((s & 1023) << 2) + (ee >> 5);   // head-row
        const size_t ai = (size_t)gr * D_MODEL + ee;
        float sum = 0.f, Ls = 0.f;
#pragma unroll
        for (int kh = 0; kh < 4; ++kh) {
            sum += Apart[(size_t)kh * (BATCH * SEQ * D_MODEL) + ai];
            Ls  += lbuf[((size_t)kh * (BATCH * NUM_HEAD) + bh) * SEQ + hr];
        }
        xs[rr][ee] = sum * (1.f / Ls);
    }
    __syncthreads();

    float acc[4] = {0.f, 0.f, 0.f, 0.f};
    const int rbase = grp * 4;
    const float4* w4 = (const float4*)wo4t;

    for (int dq = 0; dq < 32; ++dq) {
        float4 xr[4];
#pragma unroll
        for (int r = 0; r < 4; ++r) xr[r] = *(const float4*)&xs[rbase + r][dq * 4];
        const float4 w_ = w4[dq * 128 + e];
#pragma unroll
        for (int r = 0; r < 4; ++r) {
            acc[r] += xr[r].x * w_.x; acc[r] += xr[r].y * w_.y;
            acc[r] += xr[r].z * w_.z; acc[r] += xr[r].w * w_.w;
        }
    }
#pragma unroll
    for (int r = 0; r < 4; ++r)
        storef(out, (size_t)(r0 + rbase + r) * D_MODEL + e, acc[r]);
}

__global__ __launch_bounds__(256, 4) void out_proj_kernel(
    const float* __restrict__ Apart, const float* __restrict__ lbuf,
    const float* __restrict__ wo4t, void* out,
    const int* __restrict__ flag)
{
    if (*flag)
        out_proj_body<float>(Apart, lbuf, wo4t, (float*)out);
    else
        out_proj_body<__hip_bfloat16>(Apart, lbuf, wo4t, (__hip_bfloat16*)out);
}

extern "C" void kernel_launch(void* const* d_in, const int* in_sizes, int n_in,
                              void* d_out, int out_size, void* d_ws, size_t ws_size,
                              hipStream_t stream) {
    const int* seq = (const int*)d_in[0];
    const void* emb = d_in[1];
    const void* wq  = d_in[2];
    const void* wk  = d_in[3];
    const void* wv  = d_in[4];
    const void* wo  = d_in[5];

    const size_t N = (size_t)BATCH * SEQ * D_MODEL;   // 1,048,576 elements
    int*            flag = (int*)d_ws;
    unsigned short* Qhi  = (unsigned short*)((char*)d_ws + 256);
    unsigned short* Qlo  = Qhi + N;
    unsigned short* Khi  = Qlo + N;
    unsigned short* Klo  = Khi + N;
    unsigned short* Vthi = Klo + N;
    unsigned short* Vtlo = Vthi + N;
    float*          Apart = (float*)(Vtlo + N);       // 4 x [B,S,128] f32 (16 MB)
    float*          lbuf  = Apart + 4 * N;            // 4 x 8 x 4096 f32 (512 KB)
    float*          wt4   = lbuf + 4 * BATCH * NUM_HEAD * SEQ;
    float*          pe    = wt4 + 65536;              // 4096 x 128 f32 PE table

    prep_kernel<<<dim3(64 + 1024), dim3(256), 0, stream>>>(wq, wk, wv, wo, wt4, pe, flag);
    qkv_kernel<<<dim3(BATCH * SEQ / QROWS), dim3(512), 0, stream>>>(
        seq, emb, wt4, pe,
        Qhi, Qlo, Khi, Klo, Vthi, Vtlo, flag);
    attn_kernel<<<dim3(BATCH * NUM_HEAD, 64, 4), dim3(256), 0, stream>>>(
        Qhi, Qlo, Khi, Klo, Vthi, Vtlo, Apart, lbuf);
    out_proj_kernel<<<dim3(BATCH * SEQ / RROWS), dim3(256), 0, stream>>>(
        Apart, lbuf, wt4 + 49152, d_out, flag);
}

// Round 9
// 158.497 us; speedup vs baseline: 1.2468x; 1.2430x over previous
//
#include <hip/hip_runtime.h>
#include <hip/hip_bf16.h>
#include <cmath>

#define D_MODEL 128
#define NUM_HEAD 4
#define HEAD_DIM 32
#define SEQ 4096
#define BATCH 2
#define RROWS 8     // token rows per out_proj block
#define QROWS 16    // token rows per qkv block

typedef __attribute__((ext_vector_type(8))) short short8;
typedef __attribute__((ext_vector_type(4))) float f32x4;

__device__ __forceinline__ float tof(float x) { return x; }
__device__ __forceinline__ float tof(__hip_bfloat16 x) { return __bfloat162float(x); }
__device__ __forceinline__ void storef(float* p, size_t i, float v) { p[i] = v; }
__device__ __forceinline__ void storef(__hip_bfloat16* p, size_t i, float v) { p[i] = __float2bfloat16(v); }

// manual RNE split: x = hi + lo in bf16, error ~2^-18 relative
__device__ __forceinline__ void split_bf16(float x, unsigned short& hi, unsigned short& lo)
{
    const unsigned u = __float_as_uint(x);
    const unsigned r = u + 0x7FFFu + ((u >> 16) & 1u);
    hi = (unsigned short)(r >> 16);
    const float hf = __uint_as_float((unsigned)hi << 16);
    const float lf = x - hf;
    const unsigned ul = __float_as_uint(lf);
    const unsigned rl = ul + 0x7FFFu + ((ul >> 16) & 1u);
    lo = (unsigned short)(rl >> 16);
}
// hi-only RNE round (for P, whose lo term is dropped in PV)
__device__ __forceinline__ unsigned short rne_bf16(float x)
{
    const unsigned u = __float_as_uint(x);
    return (unsigned short)((u + 0x7FFFu + ((u >> 16) & 1u)) >> 16);
}

// async global->LDS, 16B per lane; dest is wave-uniform base + lane*16
__device__ __forceinline__ void g2l16(const void* g, void* l)
{
    __builtin_amdgcn_global_load_lds(
        (const __attribute__((address_space(1))) void*)g,
        (__attribute__((address_space(3))) void*)l, 16, 0, 0);
}

// ---------------------------------------------------------------------------
// Kernel 0: fused prep (unchanged).
// ---------------------------------------------------------------------------
__global__ __launch_bounds__(256) void prep_kernel(
    const void* wq, const void* wk, const void* wv, const void* wo,
    float* __restrict__ wt4, float* __restrict__ pe, int* __restrict__ flagp)
{
    const int bx  = blockIdx.x;
    const int tid = threadIdx.x;
    __shared__ int sflag;

    if (bx < 64) {
        {
            int weird = 0;
            if (tid < 64) {
                const unsigned short* w16 = (const unsigned short*)wq;
#pragma unroll
                for (int j = 0; j < 4; ++j) {
                    const unsigned short v = w16[(tid * 4 + j) * 2 + 1];
                    const float x = __uint_as_float((unsigned)v << 16);
                    const float a = fabsf(x);
                    if (a > 1e20f || (a > 0.f && a < 1e-20f)) weird++;
                }
#pragma unroll
                for (int off = 32; off; off >>= 1) weird += __shfl_xor(weird, off);
                if (tid == 0) sflag = (weird < 32) ? 1 : 0;
            }
            __syncthreads();
        }
        const int flag = sflag;
        if (bx == 0 && tid == 0) *flagp = flag;

        const int m = bx >> 4;                        // matrix 0..3
        const void* w = (m == 0) ? wq : (m == 1) ? wk : (m == 2) ? wv : wo;
        const int item = (bx & 15) * 256 + tid;       // 0..4095 float4-items
        const int e  = item & 127;
        const int dq = item >> 7;                     // 0..31
        float4 v;
        if (flag) {
            v = *(const float4*)((const float*)w + (size_t)e * 128 + dq * 4);
        } else {
            const __hip_bfloat16* wb = (const __hip_bfloat16*)w + (size_t)e * 128 + dq * 4;
            v = make_float4(tof(wb[0]), tof(wb[1]), tof(wb[2]), tof(wb[3]));
        }
        *(float4*)&wt4[(((size_t)m * 32 + dq) * 128 + e) * 4] = v;   // coalesced
    } else {
        const int item = (bx - 64) * 256 + tid;       // 0..262143
        const int s = item >> 6;                      // 0..4095
        const int i = item & 63;                      // 0..63
        const double inv = 1.0 / pow(10000.0, (double)i / 64.0);
        const double a = (double)s * inv;
        float2 sc;
        sc.x = (float)sin(a);
        sc.y = (float)cos(a);
        *(float2*)&pe[(size_t)s * 128 + i * 2] = sc;  // coalesced 8B/lane
    }
}

// ---------------------------------------------------------------------------
// Kernel 1: x = embedding[seq] + PE(table);  Q/K/V = x @ W^T, SPLIT bf16.
// (unchanged)
// ---------------------------------------------------------------------------
template <typename T>
__device__ __forceinline__ void qkv_body(
    const int* __restrict__ seq, const T* __restrict__ emb,
    const float* __restrict__ wt4, const float* __restrict__ pe,
    unsigned short* __restrict__ Qhi, unsigned short* __restrict__ Qlo,
    unsigned short* __restrict__ Khi, unsigned short* __restrict__ Klo,
    unsigned short* __restrict__ Vthi, unsigned short* __restrict__ Vtlo)
{
    const int tid = threadIdx.x;
    const int e   = tid & 127;
    const int grp = tid >> 7;                 // 0..3 -> rows grp*4 .. grp*4+3
    const int r0  = blockIdx.x * QROWS;

    __shared__ __align__(16) float xs[QROWS][D_MODEL];
    __shared__ __align__(16) unsigned short vsh[2][QROWS][D_MODEL];

#pragma unroll
    for (int k = 0; k < 4; ++k) {
        const int idx = k * 512 + tid;        // 0..2047
        const int r  = idx >> 7;
        const int ee = idx & 127;
        const int srow = r0 + r;
        xs[r][ee] = tof(emb[(size_t)seq[srow] * D_MODEL + ee])
                  + pe[(size_t)(srow & (SEQ - 1)) * D_MODEL + ee];
    }
    __syncthreads();

    float aq[4], ak[4], av[4];
#pragma unroll
    for (int r = 0; r < 4; ++r) { aq[r] = 0.f; ak[r] = 0.f; av[r] = 0.f; }

    const int rbase = grp * 4;
    const float4* wq4 = (const float4*)wt4;          // matrix stride = 4096 float4
    const float4* wk4 = wq4 + 4096;
    const float4* wv4 = wq4 + 8192;

    for (int dq = 0; dq < 32; ++dq) {
        float4 xr[4];
#pragma unroll
        for (int r = 0; r < 4; ++r) xr[r] = *(const float4*)&xs[rbase + r][dq * 4];
        const float4 wq_ = wq4[dq * 128 + e];
        const float4 wk_ = wk4[dq * 128 + e];
        const float4 wv_ = wv4[dq * 128 + e];
#pragma unroll
        for (int r = 0; r < 4; ++r) {
            aq[r] += xr[r].x * wq_.x; aq[r] += xr[r].y * wq_.y;
            aq[r] += xr[r].z * wq_.z; aq[r] += xr[r].w * wq_.w;
            ak[r] += xr[r].x * wk_.x; ak[r] += xr[r].y * wk_.y;
            ak[r] += xr[r].z * wk_.z; ak[r] += xr[r].w * wk_.w;
            av[r] += xr[r].x * wv_.x; av[r] += xr[r].y * wv_.y;
            av[r] += xr[r].z * wv_.z; av[r] += xr[r].w * wv_.w;
        }
    }

    const float scale = 0.17677669529663687f;   // 1/sqrt(32) folded into Q
#pragma unroll
    for (int r = 0; r < 4; ++r) {
        const int row = rbase + r;
        const size_t o = (size_t)(r0 + row) * D_MODEL + e;
        unsigned short hi, lo;
        split_bf16(aq[r] * scale, hi, lo); Qhi[o] = hi; Qlo[o] = lo;
        split_bf16(ak[r], hi, lo);         Khi[o] = hi; Klo[o] = lo;
        split_bf16(av[r], hi, lo);         vsh[0][row][e] = hi; vsh[1][row][e] = lo;
    }
    __syncthreads();

    // coalesced V^T store
    {
        const int b  = r0 >> 12;
        const int s0 = r0 & (SEQ - 1);
        const int h  = s0 >> 10;
        const size_t vtb = (size_t)(b * 4 + h) * (32 * SEQ);
        const int hl = tid >> 8;             // 0..1 (hi/lo plane)
        const int d  = (tid >> 3) & 31;      // head-dim
        const int j  = tid & 7;              // k-octet within 64
        short8 tmp;
#pragma unroll
        for (int i = 0; i < 8; ++i) {
            const int kl = j * 8 + i;        // 0..63
            tmp[i] = (short)vsh[hl][kl >> 2][(kl & 3) * 32 + d];
        }
        unsigned short* dst = (hl ? Vtlo : Vthi) + vtb + (size_t)d * SEQ
                            + (size_t)(s0 & 1023) * 4 + j * 8;
        *(short8*)dst = tmp;
    }
}

__global__ __launch_bounds__(512, 4) void qkv_kernel(
    const int* __restrict__ seq, const void* emb,
    const float* __restrict__ wt4, const float* __restrict__ pe,
    unsigned short* Qhi, unsigned short* Qlo,
    unsigned short* Khi, unsigned short* Klo,
    unsigned short* Vthi, unsigned short* Vtlo,
    const int* __restrict__ flag)
{
    if (*flag)
        qkv_body<float>(seq, (const float*)emb, wt4, pe,
                        Qhi, Qlo, Khi, Klo, Vthi, Vtlo);
    else
        qkv_body<__hip_bfloat16>(seq, (const __hip_bfloat16*)emb, wt4, pe,
                                 Qhi, Qlo, Khi, Klo, Vthi, Vtlo);
}

// ---------------------------------------------------------------------------
// Kernel 2 (R26): flash attention, partial-sum form (R25 grid) + cooperative
// double-buffered LDS staging of K/V via global_load_lds.
//   - The 4 rt-waves share each 32-k chunk: wave w stages plane w
//     (Khi/Klo/Vthi/Vtlo, 2KB each = 2 x 16B-per-lane instrs) -> global K/V
//     traffic /4 and the ~600cy L2/L3 latency leaves the per-chunk chain.
//   - Counted s_waitcnt vmcnt(2) (never 0 mid-loop) + raw s_barrier: buffer
//     c+1 stays in flight under chunk c's compute; compiler cannot sink this.
//   - seg-XOR swizzle (involution, applied at stage-src AND ds_read) caps
//     bank conflicts at ~4-way on the ds_read_b128 fragment reads.
//   - Math bit-identical to R25 (staging is a pure permutation copy).
// ---------------------------------------------------------------------------
__global__ __launch_bounds__(256, 6) void attn_kernel(
    const unsigned short* __restrict__ Qhi, const unsigned short* __restrict__ Qlo,
    const unsigned short* __restrict__ Khi, const unsigned short* __restrict__ Klo,
    const unsigned short* __restrict__ Vthi, const unsigned short* __restrict__ Vtlo,
    float* __restrict__ Apart, float* __restrict__ lbuf)
{
    const int bh   = blockIdx.x;
    const int by   = blockIdx.y;                  // 0..63
    const int kh   = blockIdx.z;                  // 0..3
    const int qt   = (by < 32) ? by : 95 - by;    // complementary pairing per CU
    const size_t baseQ  = (size_t)(bh >> 2) * SEQ * D_MODEL + (size_t)(bh & 3) * SEQ * HEAD_DIM;
    const size_t baseVt = (size_t)bh * (32 * SEQ);

    const int tid  = threadIdx.x;
    const int wid  = __builtin_amdgcn_readfirstlane(tid >> 6);
    const int lane = tid & 63;
    const int rt   = wid;                         // 0..3
    const int quad = lane >> 4;
    const int col  = lane & 15;

    __shared__ float shbuf[4 * 544];
    __shared__ __align__(16) unsigned char kv[2][8192];   // [buf][plane(4) x 2KB]
    float* pb = &shbuf[wid * 544];

    const int qrow0 = qt * 64 + rt * 16;

    short8 qhiF, qloF;
    {
        const size_t qo = baseQ + (size_t)(qrow0 + col) * HEAD_DIM + quad * 8;
        qhiF = *(const short8*)(Qhi + qo);
        qloF = *(const short8*)(Qlo + qo);
    }

    f32x4 O0 = {0.f, 0.f, 0.f, 0.f};
    f32x4 O1 = {0.f, 0.f, 0.f, 0.f};
    float l[4] = {0.f, 0.f, 0.f, 0.f};

    const int N   = 2 * (qt + 1);
    const int nb  = N >> 2, rem = N & 3;
    const int cnt  = nb + ((kh < rem) ? 1 : 0);
    const int cbeg = kh * nb + ((kh < rem) ? kh : rem);
    const int cend = cbeg + cnt;

    // stage one chunk's plane for this wave: 2 x (16B/lane) async copies
    const int r4 = lane >> 2, s0 = lane & 3;
    auto stage = [&](int bufi, int kbase) {
#pragma unroll
        for (int half = 0; half < 2; ++half) {
            const int row = half * 16 + r4;
            const int seg = s0 ^ (row & 3);       // pre-swizzled source (rule #21)
            const unsigned short* src;
            if (wid == 0)      src = Khi  + baseQ  + (size_t)(kbase + row) * HEAD_DIM + seg * 8;
            else if (wid == 1) src = Klo  + baseQ  + (size_t)(kbase + row) * HEAD_DIM + seg * 8;
            else if (wid == 2) src = Vthi + baseVt + (size_t)row * SEQ + kbase + seg * 8;
            else               src = Vtlo + baseVt + (size_t)row * SEQ + kbase + seg * 8;
            g2l16(src, &kv[bufi][wid * 2048 + half * 1024]);
        }
    };
    // swizzled fragment read: plane 0..3, row 0..31, quad 0..3 (16B)
    auto frag = [&](int bufi, int plane, int row) -> short8 {
        const int byte = plane * 2048 + row * 64 + ((quad ^ (row & 3)) << 4);
        return *(const short8*)(&kv[bufi][byte]);
    };

    if (cnt > 0) {
        stage(0, cbeg * 32);
        int p = 0;
        for (int c = cbeg; c < cend; ++c) {
            const int kbase = c * 32;
            const bool pre = (c + 1 < cend);
            if (pre) {
                stage(p ^ 1, (c + 1) * 32);
                asm volatile("s_waitcnt vmcnt(2)" ::: "memory");
            } else {
                asm volatile("s_waitcnt vmcnt(0)" ::: "memory");
            }
            __builtin_amdgcn_s_barrier();         // all 4 planes of buf[p] ready

            const short8 k0h = frag(p, 0, col);
            const short8 k0l = frag(p, 1, col);
            const short8 k1h = frag(p, 0, col + 16);
            const short8 k1l = frag(p, 1, col + 16);

            f32x4 s0v = {0.f, 0.f, 0.f, 0.f};
            f32x4 s1v = {0.f, 0.f, 0.f, 0.f};
            s0v = __builtin_amdgcn_mfma_f32_16x16x32_bf16(qhiF, k0h, s0v, 0, 0, 0);
            s0v = __builtin_amdgcn_mfma_f32_16x16x32_bf16(qhiF, k0l, s0v, 0, 0, 0);
            s0v = __builtin_amdgcn_mfma_f32_16x16x32_bf16(qloF, k0h, s0v, 0, 0, 0);
            s1v = __builtin_amdgcn_mfma_f32_16x16x32_bf16(qhiF, k1h, s1v, 0, 0, 0);
            s1v = __builtin_amdgcn_mfma_f32_16x16x32_bf16(qhiF, k1l, s1v, 0, 0, 0);
            s1v = __builtin_amdgcn_mfma_f32_16x16x32_bf16(qloF, k1h, s1v, 0, 0, 0);

            // fixed m=0 softmax numerator: e = exp(|s|) where unmasked, else 0
#pragma unroll
            for (int r = 0; r < 4; ++r) {
                const int rowg = qrow0 + quad * 4 + r;
                const float e0 = (kbase + col      <= rowg) ? __expf(fabsf(s0v[r])) : 0.f;
                const float e1 = (kbase + 16 + col <= rowg) ? __expf(fabsf(s1v[r])) : 0.f;
                l[r] += e0 + e1;
                pb[(quad * 4 + r) * 34 + col]      = e0;
                pb[(quad * 4 + r) * 34 + 16 + col] = e1;
            }
            short8 ph;
            {
                const float* pr = &pb[col * 34 + quad * 8];
#pragma unroll
                for (int j = 0; j < 8; ++j) ph[j] = (short)rne_bf16(pr[j]);
            }

            const short8 v0h = frag(p, 2, col);
            const short8 v0l = frag(p, 3, col);
            const short8 v1h = frag(p, 2, col + 16);
            const short8 v1l = frag(p, 3, col + 16);

            O0 = __builtin_amdgcn_mfma_f32_16x16x32_bf16(ph, v0h, O0, 0, 0, 0);
            O0 = __builtin_amdgcn_mfma_f32_16x16x32_bf16(ph, v0l, O0, 0, 0, 0);
            O1 = __builtin_amdgcn_mfma_f32_16x16x32_bf16(ph, v1h, O1, 0, 0, 0);
            O1 = __builtin_amdgcn_mfma_f32_16x16x32_bf16(ph, v1l, O1, 0, 0, 0);

            __builtin_amdgcn_s_barrier();         // buf[p] free for restage
            p ^= 1;
        }
    }

    // row-sum of l across the 16 cols
#pragma unroll
    for (int off = 1; off < 16; off <<= 1) {
#pragma unroll
        for (int r = 0; r < 4; ++r) l[r] += __shfl_xor(l[r], off, 64);
    }

    // direct partial writes -- no cross-wave combine
    float* Ap = Apart + (size_t)kh * (BATCH * SEQ * D_MODEL) + baseQ;
#pragma unroll
    for (int r = 0; r < 4; ++r) {
        const int row = qrow0 + quad * 4 + r;
        Ap[(size_t)row * HEAD_DIM + col]      = O0[r];
        Ap[(size_t)row * HEAD_DIM + 16 + col] = O1[r];
    }
    if (col == 0) {
        float* lp = lbuf + ((size_t)kh * (BATCH * NUM_HEAD) + bh) * SEQ;
#pragma unroll
        for (int r = 0; r < 4; ++r)
            lp[qrow0 + quad * 4 + r] = l[r];
    }
}

// ---------------------------------------------------------------------------
// Kernel 3 (R25): out = att @ Wo^T, 4-way kh partial sum + 1/L folded in.
// ---------------------------------------------------------------------------
template <typename T>
__device__ __forceinline__ void out_proj_body(
    const float* __restrict__ Apart, const float* __restrict__ lbuf,
    const float* __restrict__ wo4t, T* __restrict__ out)
{
    const int tid = threadIdx.x;
    const int e   = tid & 127;
    const int grp = tid >> 7;                 // 0..1 -> rows grp*4 .. grp*4+3
    const int r0  = blockIdx.x * RROWS;

    __shared__ __align__(16) float xs[RROWS][D_MODEL];
#pragma unroll
    for (int k = 0; k < 4; ++k) {
        const int idx = k * 256 + tid;        // 0..1023
        const int rr = idx >> 7;
        const int ee = idx & 127;
        const int gr = r0 + rr;               // global token row
        const int b  = gr >> 12;
        const int s  = gr & (SEQ - 1);
        const int bh = b * 4 + (s >> 10);
        const int hr = ((s & 1023) << 2) + (ee >> 5);   // head-row
        const size_t ai = (size_t)gr * D_MODEL + ee;
        float sum = 0.f, Ls = 0.f;
#pragma unroll
        for (int kh = 0; kh < 4; ++kh) {
            sum += Apart[(size_t)kh * (BATCH * SEQ * D_MODEL) + ai];
            Ls  += lbuf[((size_t)kh * (BATCH * NUM_HEAD) + bh) * SEQ + hr];
        }
        xs[rr][ee] = sum * (1.f / Ls);
    }
    __syncthreads();

    float acc[4] = {0.f, 0.f, 0.f, 0.f};
    const int rbase = grp * 4;
    const float4* w4 = (const float4*)wo4t;

    for (int dq = 0; dq < 32; ++dq) {
        float4 xr[4];
#pragma unroll
        for (int r = 0; r < 4; ++r) xr[r] = *(const float4*)&xs[rbase + r][dq * 4];
        const float4 w_ = w4[dq * 128 + e];
#pragma unroll
        for (int r = 0; r < 4; ++r) {
            acc[r] += xr[r].x * w_.x; acc[r] += xr[r].y * w_.y;
            acc[r] += xr[r].z * w_.z; acc[r] += xr[r].w * w_.w;
        }
    }
#pragma unroll
    for (int r = 0; r < 4; ++r)
        storef(out, (size_t)(r0 + rbase + r) * D_MODEL + e, acc[r]);
}

__global__ __launch_bounds__(256, 4) void out_proj_kernel(
    const float* __restrict__ Apart, const float* __restrict__ lbuf,
    const float* __restrict__ wo4t, void* out,
    const int* __restrict__ flag)
{
    if (*flag)
        out_proj_body<float>(Apart, lbuf, wo4t, (float*)out);
    else
        out_proj_body<__hip_bfloat16>(Apart, lbuf, wo4t, (__hip_bfloat16*)out);
}

extern "C" void kernel_launch(void* const* d_in, const int* in_sizes, int n_in,
                              void* d_out, int out_size, void* d_ws, size_t ws_size,
                              hipStream_t stream) {
    const int* seq = (const int*)d_in[0];
    const void* emb = d_in[1];
    const void* wq  = d_in[2];
    const void* wk  = d_in[3];
    const void* wv  = d_in[4];
    const void* wo  = d_in[5];

    const size_t N = (size_t)BATCH * SEQ * D_MODEL;   // 1,048,576 elements
    int*            flag = (int*)d_ws;
    unsigned short* Qhi  = (unsigned short*)((char*)d_ws + 256);
    unsigned short* Qlo  = Qhi + N;
    unsigned short* Khi  = Qlo + N;
    unsigned short* Klo  = Khi + N;
    unsigned short* Vthi = Klo + N;
    unsigned short* Vtlo = Vthi + N;
    float*          Apart = (float*)(Vtlo + N);       // 4 x [B,S,128] f32 (16 MB)
    float*          lbuf  = Apart + 4 * N;            // 4 x 8 x 4096 f32 (512 KB)
    float*          wt4   = lbuf + 4 * BATCH * NUM_HEAD * SEQ;
    float*          pe    = wt4 + 65536;              // 4096 x 128 f32 PE table

    prep_kernel<<<dim3(64 + 1024), dim3(256), 0, stream>>>(wq, wk, wv, wo, wt4, pe, flag);
    qkv_kernel<<<dim3(BATCH * SEQ / QROWS), dim3(512), 0, stream>>>(
        seq, emb, wt4, pe,
        Qhi, Qlo, Khi, Klo, Vthi, Vtlo, flag);
    attn_kernel<<<dim3(BATCH * NUM_HEAD, 64, 4), dim3(256), 0, stream>>>(
        Qhi, Qlo, Khi, Klo, Vthi, Vtlo, Apart, lbuf);
    out_proj_kernel<<<dim3(BATCH * SEQ / RROWS), dim3(256), 0, stream>>>(
        Apart, lbuf, wt4 + 49152, d_out, flag);
}